// Round 1
// baseline (3987.717 us; speedup 1.0000x reference)
//
#include <hip/hip_runtime.h>

namespace {

constexpr int kB = 8;
constexpr int kC = 1024;
constexpr int kT = 1500;
constexpr int kK = 8192;
constexpr int kD = 256;
constexpr int kH = 512;
constexpr int kNQ = 4;
constexpr int kBins = 1024;
constexpr int kN = kB * kT;       // 12000 frames
constexpr float kEps = 1e-8f;
constexpr float kSlope = 0.01f;

using u64 = unsigned long long;

__device__ __forceinline__ unsigned ordered_bits(float f) {
  unsigned b = __float_as_uint(f);
  return (b & 0x80000000u) ? ~b : (b | 0x80000000u);
}

// ---------------- (B,C,T) -> row-major (B*T, C) ----------------
__global__ __launch_bounds__(256) void transpose_in(const float* __restrict__ f,
                                                    float* __restrict__ X) {
  __shared__ float tile[32][33];
  const int t0 = blockIdx.x * 32, c0 = blockIdx.y * 32, b = blockIdx.z;
  const int tx = threadIdx.x, ty = threadIdx.y;
#pragma unroll
  for (int i = 0; i < 4; ++i) {
    const int cl = ty + i * 8;
    if (t0 + tx < kT)
      tile[cl][tx] = f[(size_t)b * kC * kT + (size_t)(c0 + cl) * kT + (t0 + tx)];
  }
  __syncthreads();
#pragma unroll
  for (int i = 0; i < 4; ++i) {
    const int tl = ty + i * 8;
    if (t0 + tl < kT)
      X[(size_t)(b * kT + t0 + tl) * kC + (c0 + tx)] = tile[tx][tl];
  }
}

// ---------------- per-row squared norms ----------------
__global__ __launch_bounds__(256) void row_sqsum(const float* __restrict__ A,
                                                 float* __restrict__ S, int Kd) {
  const int r = blockIdx.x;
  const float4* a4 = reinterpret_cast<const float4*>(A + (size_t)r * Kd);
  float s = 0.f;
  for (int i = threadIdx.x; i < (Kd >> 2); i += 256) {
    const float4 v = a4[i];
    s = fmaf(v.x, v.x, s); s = fmaf(v.y, v.y, s);
    s = fmaf(v.z, v.z, s); s = fmaf(v.w, v.w, s);
  }
#pragma unroll
  for (int off = 32; off > 0; off >>= 1) s += __shfl_down(s, off, 64);
  __shared__ float ws[4];
  const int lane = threadIdx.x & 63, w = threadIdx.x >> 6;
  if (lane == 0) ws[w] = s;
  __syncthreads();
  if (threadIdx.x == 0) S[r] = (ws[0] + ws[1]) + (ws[2] + ws[3]);
}

// ---------------- fused distance-GEMM + argmin ----------------
// dist[m][n] = (S[m] - 2*dot(A[m], table[n])) + cc[n]   (fp32, same assoc as ref)
// 128x128 tile, 256 threads, 8x8 microtile. Result: per-row min via packed
// (ordered_bits(dist)<<32 | col) and global 64-bit atomicMin (ties -> lowest idx,
// matching jnp.argmin first-occurrence semantics).
__global__ __launch_bounds__(256) void vq_argmin(
    const float* __restrict__ A, const float* __restrict__ table,
    const float* __restrict__ cc, const float* __restrict__ S,
    u64* __restrict__ keys, int M, int Kd) {
  __shared__ float As[16][128];
  __shared__ float Ts[16][128];
  __shared__ u64 red[128][16];
  const int m0 = blockIdx.x * 128, n0 = blockIdx.y * 128;
  const int t = threadIdx.x;
  const int tx = t & 15, ty = t >> 4;       // 16 col-groups x 16 row-groups
  const int lrow = t >> 1, lk8 = (t & 1) * 8;
  float acc[8][8] = {};
  for (int k0 = 0; k0 < Kd; k0 += 16) {
    // stage A (128 rows x 16 k) and table (128 cols x 16 k), 8 floats/thread each
    const int gm = m0 + lrow;
    float4 a0 = make_float4(0.f, 0.f, 0.f, 0.f), a1 = a0;
    if (gm < M) {
      const float* ap = &A[(size_t)gm * Kd + (k0 + lk8)];
      a0 = *reinterpret_cast<const float4*>(ap);
      a1 = *reinterpret_cast<const float4*>(ap + 4);
    }
    const float* tp = &table[(size_t)(n0 + lrow) * Kd + (k0 + lk8)];
    const float4 b0 = *reinterpret_cast<const float4*>(tp);
    const float4 b1 = *reinterpret_cast<const float4*>(tp + 4);
    As[lk8 + 0][lrow] = a0.x; As[lk8 + 1][lrow] = a0.y;
    As[lk8 + 2][lrow] = a0.z; As[lk8 + 3][lrow] = a0.w;
    As[lk8 + 4][lrow] = a1.x; As[lk8 + 5][lrow] = a1.y;
    As[lk8 + 6][lrow] = a1.z; As[lk8 + 7][lrow] = a1.w;
    Ts[lk8 + 0][lrow] = b0.x; Ts[lk8 + 1][lrow] = b0.y;
    Ts[lk8 + 2][lrow] = b0.z; Ts[lk8 + 3][lrow] = b0.w;
    Ts[lk8 + 4][lrow] = b1.x; Ts[lk8 + 5][lrow] = b1.y;
    Ts[lk8 + 6][lrow] = b1.z; Ts[lk8 + 7][lrow] = b1.w;
    __syncthreads();
#pragma unroll
    for (int kk = 0; kk < 16; ++kk) {
      float ar[8], br[8];
      *reinterpret_cast<float4*>(&ar[0]) = *reinterpret_cast<const float4*>(&As[kk][ty * 8]);
      *reinterpret_cast<float4*>(&ar[4]) = *reinterpret_cast<const float4*>(&As[kk][ty * 8 + 4]);
      *reinterpret_cast<float4*>(&br[0]) = *reinterpret_cast<const float4*>(&Ts[kk][tx * 8]);
      *reinterpret_cast<float4*>(&br[4]) = *reinterpret_cast<const float4*>(&Ts[kk][tx * 8 + 4]);
#pragma unroll
      for (int i = 0; i < 8; ++i)
#pragma unroll
        for (int j = 0; j < 8; ++j) acc[i][j] = fmaf(ar[i], br[j], acc[i][j]);
    }
    __syncthreads();
  }
  // epilogue: distances + per-row argmin
  float ccv[8];
  *reinterpret_cast<float4*>(&ccv[0]) = *reinterpret_cast<const float4*>(&cc[n0 + tx * 8]);
  *reinterpret_cast<float4*>(&ccv[4]) = *reinterpret_cast<const float4*>(&cc[n0 + tx * 8 + 4]);
#pragma unroll
  for (int i = 0; i < 8; ++i) {
    const int gm = m0 + ty * 8 + i;
    const float Srow = (gm < M) ? S[gm] : 0.f;
    u64 best = ~0ull;
#pragma unroll
    for (int j = 0; j < 8; ++j) {
      const int gn = n0 + tx * 8 + j;
      const float d = (Srow - 2.0f * acc[i][j]) + ccv[j];   // exact ref assoc
      const u64 key = ((u64)ordered_bits(d) << 32) | (unsigned)gn;
      best = (key < best) ? key : best;
    }
    red[ty * 8 + i][tx] = best;
  }
  __syncthreads();
  if (t < 128) {
    u64 b = red[t][0];
#pragma unroll
    for (int j = 1; j < 16; ++j) { const u64 v = red[t][j]; b = (v < b) ? v : b; }
    const int gm = m0 + t;
    if (gm < M) atomicMin(&keys[gm], b);
  }
}

// ---------------- gather centroid + form residual (in-place on X) ----------------
__global__ __launch_bounds__(256) void gather_residual(
    const float* __restrict__ centroid, const u64* __restrict__ keys,
    float* __restrict__ X, float* __restrict__ lin_dec) {
  const int i4 = blockIdx.x * 256 + threadIdx.x;   // over N*C/4
  const int n = i4 >> 8;          // C/4 = 256 float4 per row
  const int c4 = (i4 & 255) << 2;
  const unsigned idx = (unsigned)(keys[n] & 0xffffffffu);
  const float4 cv = *reinterpret_cast<const float4*>(&centroid[(size_t)idx * kC + c4]);
  float4 xv = *reinterpret_cast<const float4*>(&X[(size_t)n * kC + c4]);
  xv.x -= cv.x; xv.y -= cv.y; xv.z -= cv.z; xv.w -= cv.w;
  *reinterpret_cast<float4*>(&lin_dec[(size_t)n * kC + c4]) = cv;
  *reinterpret_cast<float4*>(&X[(size_t)n * kC + c4]) = xv;
}

// ---------------- generic GEMM: out = act(A @ W + bias) ----------------
template <int ACT>   // 0 = none, 1 = leaky relu, 2 = relu
__global__ __launch_bounds__(256) void gemm_bias_act(
    const float* __restrict__ A, const float* __restrict__ W,
    const float* __restrict__ bias, float* __restrict__ out,
    int M, int Nc, int Kd) {
  __shared__ float As[16][64];
  __shared__ float Ws[16][64];
  const int m0 = blockIdx.x * 64, n0 = blockIdx.y * 64;
  const int t = threadIdx.x;
  const int tx = t & 15, ty = t >> 4;
  const int arow = t >> 2, ak4 = (t & 3) << 2;
  const int wk = t >> 4, wn4 = (t & 15) << 2;
  float acc[4][4] = {};
  for (int k0 = 0; k0 < Kd; k0 += 16) {
    float4 av = make_float4(0.f, 0.f, 0.f, 0.f);
    const int gm = m0 + arow;
    if (gm < M) av = *reinterpret_cast<const float4*>(&A[(size_t)gm * Kd + (k0 + ak4)]);
    As[ak4 + 0][arow] = av.x; As[ak4 + 1][arow] = av.y;
    As[ak4 + 2][arow] = av.z; As[ak4 + 3][arow] = av.w;
    *reinterpret_cast<float4*>(&Ws[wk][wn4]) =
        *reinterpret_cast<const float4*>(&W[(size_t)(k0 + wk) * Nc + (n0 + wn4)]);
    __syncthreads();
#pragma unroll
    for (int kk = 0; kk < 16; ++kk) {
      float ar[4], br[4];
      *reinterpret_cast<float4*>(ar) = *reinterpret_cast<const float4*>(&As[kk][ty << 2]);
      *reinterpret_cast<float4*>(br) = *reinterpret_cast<const float4*>(&Ws[kk][tx << 2]);
#pragma unroll
      for (int i = 0; i < 4; ++i)
#pragma unroll
        for (int j = 0; j < 4; ++j) acc[i][j] = fmaf(ar[i], br[j], acc[i][j]);
    }
    __syncthreads();
  }
  float bv[4];
  *reinterpret_cast<float4*>(bv) = *reinterpret_cast<const float4*>(&bias[n0 + (tx << 2)]);
#pragma unroll
  for (int i = 0; i < 4; ++i) {
    const int gm = m0 + (ty << 2) + i;
    if (gm >= M) continue;
    float o[4];
#pragma unroll
    for (int j = 0; j < 4; ++j) {
      float v = acc[i][j] + bv[j];
      if (ACT == 1) v = (v >= 0.f) ? v : kSlope * v;
      if (ACT == 2) v = fmaxf(v, 0.f);
      o[j] = v;
    }
    *reinterpret_cast<float4*>(&out[(size_t)gm * Nc + n0 + (tx << 2)]) =
        *reinterpret_cast<const float4*>(o);
  }
}

// ---------------- resid = enc/(norm+eps); qsum = 0 ----------------
__global__ __launch_bounds__(256) void norm_div_init(
    const float* __restrict__ e, const float* __restrict__ nv,
    float* __restrict__ resid, float* __restrict__ qsum) {
  const int i = blockIdx.x * 256 + threadIdx.x;   // over N*D/4
  const float4 ev = reinterpret_cast<const float4*>(e)[i];
  const float4 vv = reinterpret_cast<const float4*>(nv)[i];
  float4 r;
  r.x = ev.x / (vv.x + kEps); r.y = ev.y / (vv.y + kEps);
  r.z = ev.z / (vv.z + kEps); r.w = ev.w / (vv.w + kEps);
  reinterpret_cast<float4*>(resid)[i] = r;
  reinterpret_cast<float4*>(qsum)[i] = make_float4(0.f, 0.f, 0.f, 0.f);
}

// ---------------- q = cb[idx]; qsum += q; resid -= q ----------------
__global__ __launch_bounds__(256) void rvq_update(
    const float* __restrict__ cb, const u64* __restrict__ keys,
    float* __restrict__ resid, float* __restrict__ qsum) {
  const int i4 = blockIdx.x * 256 + threadIdx.x;  // over N*D/4
  const int n = i4 >> 6;          // D/4 = 64 float4 per row
  const int d4 = (i4 & 63) << 2;
  const unsigned idx = (unsigned)(keys[n] & 0xffffffffu);
  const float4 q = *reinterpret_cast<const float4*>(&cb[(size_t)idx * kD + d4]);
  float4 r = reinterpret_cast<float4*>(resid)[i4];
  float4 s = reinterpret_cast<float4*>(qsum)[i4];
  r.x -= q.x; r.y -= q.y; r.z -= q.z; r.w -= q.w;
  s.x += q.x; s.y += q.y; s.z += q.z; s.w += q.w;
  reinterpret_cast<float4*>(resid)[i4] = r;
  reinterpret_cast<float4*>(qsum)[i4] = s;
}

// ---------------- dec_in = qsum * norm_vec ----------------
__global__ __launch_bounds__(256) void denorm(
    const float* __restrict__ qsum, const float* __restrict__ nv,
    float* __restrict__ o) {
  const int i = blockIdx.x * 256 + threadIdx.x;   // over N*D/4
  const float4 q = reinterpret_cast<const float4*>(qsum)[i];
  const float4 v = reinterpret_cast<const float4*>(nv)[i];
  float4 r;
  r.x = q.x * v.x; r.y = q.y * v.y; r.z = q.z * v.z; r.w = q.w * v.w;
  reinterpret_cast<float4*>(o)[i] = r;
}

// ---------------- out[b,c,t] = lin_dec[n,c] + dec_out[n,c] ----------------
__global__ __launch_bounds__(256) void final_out(const float* __restrict__ lin_dec,
                                                 const float* __restrict__ dec_out,
                                                 float* __restrict__ out) {
  __shared__ float tile[32][33];
  const int t0 = blockIdx.x * 32, c0 = blockIdx.y * 32, b = blockIdx.z;
  const int tx = threadIdx.x, ty = threadIdx.y;
#pragma unroll
  for (int i = 0; i < 4; ++i) {
    const int tl = ty + i * 8;
    if (t0 + tl < kT) {
      const size_t idx = (size_t)(b * kT + t0 + tl) * kC + (c0 + tx);
      tile[tl][tx] = lin_dec[idx] + dec_out[idx];
    }
  }
  __syncthreads();
#pragma unroll
  for (int i = 0; i < 4; ++i) {
    const int cl = ty + i * 8;
    if (t0 + tx < kT)
      out[(size_t)b * kC * kT + (size_t)(c0 + cl) * kT + (t0 + tx)] = tile[tx][cl];
  }
}

}  // namespace

extern "C" void kernel_launch(void* const* d_in, const int* in_sizes, int n_in,
                              void* d_out, int out_size, void* d_ws, size_t ws_size,
                              hipStream_t stream) {
  (void)in_sizes; (void)n_in; (void)out_size; (void)ws_size;
  const float* feature  = (const float*)d_in[0];
  const float* centroid = (const float*)d_in[1];
  const float* enc_w0 = (const float*)d_in[2];  const float* enc_b0 = (const float*)d_in[3];
  const float* enc_w1 = (const float*)d_in[4];  const float* enc_b1 = (const float*)d_in[5];
  const float* enc_w2 = (const float*)d_in[6];  const float* enc_b2 = (const float*)d_in[7];
  const float* dec_w0 = (const float*)d_in[8];  const float* dec_b0 = (const float*)d_in[9];
  const float* dec_w1 = (const float*)d_in[10]; const float* dec_b1 = (const float*)d_in[11];
  const float* dec_w2 = (const float*)d_in[12]; const float* dec_b2 = (const float*)d_in[13];
  const float* nrm_w0 = (const float*)d_in[14]; const float* nrm_b0 = (const float*)d_in[15];
  const float* nrm_w1 = (const float*)d_in[16]; const float* nrm_b1 = (const float*)d_in[17];
  const float* nrm_w2 = (const float*)d_in[18]; const float* nrm_b2 = (const float*)d_in[19];
  const float* codebooks = (const float*)d_in[20];
  float* out = (float*)d_out;

  // workspace layout (~197 MB total)
  float* X       = (float*)d_ws;                 // N*C   : x_flat -> spk_raw -> dec_out
  float* lin_dec = X       + (size_t)kN * kC;    // N*C
  float* h0      = lin_dec + (size_t)kN * kC;    // N*H
  float* h1      = h0      + (size_t)kN * kH;    // N*H
  float* e_out   = h1      + (size_t)kN * kH;    // N*D  : spk_enc -> dec_in
  float* nvec    = e_out   + (size_t)kN * kD;    // N*D
  float* resid   = nvec    + (size_t)kN * kD;    // N*D
  float* qsum    = resid   + (size_t)kN * kD;    // N*D
  float* Srow    = qsum    + (size_t)kN * kD;    // N
  float* ccbuf   = Srow    + kN;                 // max(K, BINS)
  u64*   keys    = (u64*)(ccbuf + kK);           // N packed (dist,idx)

  const dim3 tb32(32, 8);
  const dim3 tgT((kT + 31) / 32, kC / 32, kB);

  // feature (B,C,T) -> X (N,C)
  transpose_in<<<tgT, tb32, 0, stream>>>(feature, X);

  // ---- linguistic VQ ----
  row_sqsum<<<kN, 256, 0, stream>>>(X, Srow, kC);
  row_sqsum<<<kK, 256, 0, stream>>>(centroid, ccbuf, kC);
  hipMemsetAsync(keys, 0xFF, (size_t)kN * sizeof(u64), stream);
  vq_argmin<<<dim3((kN + 127) / 128, kK / 128), 256, 0, stream>>>(
      X, centroid, ccbuf, Srow, keys, kN, kC);
  gather_residual<<<kN * kC / 4 / 256, 256, 0, stream>>>(centroid, keys, X, lin_dec);

  const dim3 gH((kN + 63) / 64, kH / 64);
  const dim3 gD((kN + 63) / 64, kD / 64);
  const dim3 gC((kN + 63) / 64, kC / 64);

  // ---- encoder (leaky, leaky, none) on spk_raw (X) ----
  gemm_bias_act<1><<<gH, 256, 0, stream>>>(X,  enc_w0, enc_b0, h0,    kN, kH, kC);
  gemm_bias_act<1><<<gH, 256, 0, stream>>>(h0, enc_w1, enc_b1, h1,    kN, kH, kH);
  gemm_bias_act<0><<<gD, 256, 0, stream>>>(h1, enc_w2, enc_b2, e_out, kN, kD, kH);

  // ---- normalizer (relu x3) on lin_dec ----
  gemm_bias_act<2><<<gH, 256, 0, stream>>>(lin_dec, nrm_w0, nrm_b0, h0,   kN, kH, kC);
  gemm_bias_act<2><<<gH, 256, 0, stream>>>(h0,      nrm_w1, nrm_b1, h1,   kN, kH, kH);
  gemm_bias_act<2><<<gD, 256, 0, stream>>>(h1,      nrm_w2, nrm_b2, nvec, kN, kD, kH);

  norm_div_init<<<kN * kD / 4 / 256, 256, 0, stream>>>(e_out, nvec, resid, qsum);

  // ---- RVQ: 4 stages ----
  for (int q = 0; q < kNQ; ++q) {
    const float* cb = codebooks + (size_t)q * kBins * kD;
    row_sqsum<<<kN, 256, 0, stream>>>(resid, Srow, kD);
    row_sqsum<<<kBins, 256, 0, stream>>>(cb, ccbuf, kD);
    hipMemsetAsync(keys, 0xFF, (size_t)kN * sizeof(u64), stream);
    vq_argmin<<<dim3((kN + 127) / 128, kBins / 128), 256, 0, stream>>>(
        resid, cb, ccbuf, Srow, keys, kN, kD);
    rvq_update<<<kN * kD / 4 / 256, 256, 0, stream>>>(cb, keys, resid, qsum);
  }

  // quantized (fwd) = qsum; denorm into decoder input
  denorm<<<kN * kD / 4 / 256, 256, 0, stream>>>(qsum, nvec, e_out);

  // ---- decoder (leaky, leaky, none) ----
  gemm_bias_act<1><<<gH, 256, 0, stream>>>(e_out, dec_w0, dec_b0, h0, kN, kH, kD);
  gemm_bias_act<1><<<gH, 256, 0, stream>>>(h0,    dec_w1, dec_b1, h1, kN, kH, kH);
  gemm_bias_act<0><<<gC, 256, 0, stream>>>(h1,    dec_w2, dec_b2, X,  kN, kC, kH);

  // out = lin_dec + spk_dec, back to (B,C,T)
  final_out<<<tgT, tb32, 0, stream>>>(lin_dec, X, out);
}

// Round 4
// 2794.031 us; speedup vs baseline: 1.4272x; 1.4272x over previous
//
#include <hip/hip_runtime.h>

namespace {

constexpr int kB = 8;
constexpr int kC = 1024;
constexpr int kT = 1500;
constexpr int kK = 8192;
constexpr int kD = 256;
constexpr int kH = 512;
constexpr int kNQ = 4;
constexpr int kBins = 1024;
constexpr int kN = kB * kT;       // 12000 frames
constexpr float kEps = 1e-8f;
constexpr float kSlope = 0.01f;
constexpr float kMargin = 8.0f;    // ~28-57 sigma of bf16-hh distance error
constexpr unsigned kCap = 4194304; // candidate capacity (16 MB, in lin_dec region)

using u64 = unsigned long long;
typedef __attribute__((ext_vector_type(8))) short bf16x8;
typedef __attribute__((ext_vector_type(4))) float f32x4;

__device__ __forceinline__ unsigned ordered_bits(float f) {
  unsigned b = __float_as_uint(f);
  return (b & 0x80000000u) ? ~b : (b | 0x80000000u);
}
__device__ __forceinline__ float unordered_bits(unsigned b) {
  return __uint_as_float((b & 0x80000000u) ? (b ^ 0x80000000u) : ~b);
}
__device__ __forceinline__ unsigned short f2bf(float f) {  // RNE
  unsigned u = __float_as_uint(f);
  return (unsigned short)((u + 0x7fffu + ((u >> 16) & 1u)) >> 16);
}
__device__ __forceinline__ void gl_lds16(const void* g, void* l) {
  __builtin_amdgcn_global_load_lds(
      (const __attribute__((address_space(1))) void*)g,
      (__attribute__((address_space(3))) void*)l, 16, 0, 0);
}

// ---------------- (B,C,T) -> row-major (B*T, C) ----------------
__global__ __launch_bounds__(256) void transpose_in(const float* __restrict__ f,
                                                    float* __restrict__ X) {
  __shared__ float tile[32][33];
  const int t0 = blockIdx.x * 32, c0 = blockIdx.y * 32, b = blockIdx.z;
  const int tx = threadIdx.x, ty = threadIdx.y;
#pragma unroll
  for (int i = 0; i < 4; ++i) {
    const int cl = ty + i * 8;
    if (t0 + tx < kT)
      tile[cl][tx] = f[(size_t)b * kC * kT + (size_t)(c0 + cl) * kT + (t0 + tx)];
  }
  __syncthreads();
#pragma unroll
  for (int i = 0; i < 4; ++i) {
    const int tl = ty + i * 8;
    if (t0 + tl < kT)
      X[(size_t)(b * kT + t0 + tl) * kC + (c0 + tx)] = tile[tx][tl];
  }
}

// ---------------- fp32 -> bf16 convert ----------------
__global__ __launch_bounds__(256) void to_bf16(const float* __restrict__ in,
                                               unsigned short* __restrict__ out,
                                               int n4) {
  const int i = blockIdx.x * 256 + threadIdx.x;
  if (i >= n4) return;
  const float4 v = reinterpret_cast<const float4*>(in)[i];
  ushort4 o;
  o.x = f2bf(v.x); o.y = f2bf(v.y); o.z = f2bf(v.z); o.w = f2bf(v.w);
  reinterpret_cast<ushort4*>(out)[i] = o;
}

// ---------------- per-row squared norms ----------------
__global__ __launch_bounds__(256) void row_sqsum(const float* __restrict__ A,
                                                 float* __restrict__ S, int Kd) {
  const int r = blockIdx.x;
  const float4* a4 = reinterpret_cast<const float4*>(A + (size_t)r * Kd);
  float s = 0.f;
  for (int i = threadIdx.x; i < (Kd >> 2); i += 256) {
    const float4 v = a4[i];
    s = fmaf(v.x, v.x, s); s = fmaf(v.y, v.y, s);
    s = fmaf(v.z, v.z, s); s = fmaf(v.w, v.w, s);
  }
#pragma unroll
  for (int off = 32; off > 0; off >>= 1) s += __shfl_down(s, off, 64);
  __shared__ float ws[4];
  const int lane = threadIdx.x & 63, w = threadIdx.x >> 6;
  if (lane == 0) ws[w] = s;
  __syncthreads();
  if (threadIdx.x == 0) S[r] = (ws[0] + ws[1]) + (ws[2] + ws[3]);
}

// ---------------- linguistic VQ: bf16 MFMA approx pass ----------------
// 128x128 tile, 256 thr (4 waves, 2x2), 16x16x32 bf16 MFMA, K=1024.
// global_load_lds(16B) with inverse-swizzled global source; swizzled
// ds_read_b128 (2-way bank aliasing = free). Epilogue phase 1: per-row
// atomicMin of approx dist. __threadfence() (drains own atomics + invalidates
// L1 so rowmin[gr] >= own posted panel-min is guaranteed visible — without it
// the plain load may legally return the 0xFF init => NaN thr => dropped
// candidates). Phase 2: append all cols within kMargin of the observed
// row-min (superset of exact candidate set for any atomic interleaving).
__global__ __launch_bounds__(256) void lin_vq_mfma(
    const unsigned short* __restrict__ Ah, const unsigned short* __restrict__ Bh,
    const float* __restrict__ S, const float* __restrict__ cc,
    unsigned* __restrict__ rowmin, unsigned* __restrict__ cands,
    unsigned* __restrict__ counter, int M) {
  __shared__ __attribute__((aligned(16))) unsigned short lsa[128 * 32];
  __shared__ __attribute__((aligned(16))) unsigned short lsb[128 * 32];
  const int t = threadIdx.x;
  const int l = t & 63, w = t >> 6;
  const int wr = w >> 1, wc = w & 1;
  const int m0 = blockIdx.x * 128, n0 = blockIdx.y * 128;
  const int rl = l & 15, lh = l >> 4;
  const int srow = l >> 2, sp = l & 3;     // staging: lane -> (row, phys slot)
  f32x4 acc[4][4] = {};
  for (int k0 = 0; k0 < kC; k0 += 32) {
#pragma unroll
    for (int i = 0; i < 2; ++i) {
      const int rb = (w * 2 + i) * 16;
      const int r = rb + srow;
      const int s = (sp - ((r >> 1) & 3)) & 3;   // logical slot for phys sp
      gl_lds16(Ah + ((size_t)(m0 + r) * kC + k0 + s * 8), &lsa[rb * 32]);
      gl_lds16(Bh + ((size_t)(n0 + r) * kC + k0 + s * 8), &lsb[rb * 32]);
    }
    __syncthreads();
    bf16x8 a[4], b[4];
#pragma unroll
    for (int m = 0; m < 4; ++m) {
      const int r = wr * 64 + m * 16 + rl;
      const int pp = (lh + ((r >> 1) & 3)) & 3;
      a[m] = *reinterpret_cast<const bf16x8*>(&lsa[r * 32 + pp * 8]);
    }
#pragma unroll
    for (int n = 0; n < 4; ++n) {
      const int r = wc * 64 + n * 16 + rl;
      const int pp = (lh + ((r >> 1) & 3)) & 3;
      b[n] = *reinterpret_cast<const bf16x8*>(&lsb[r * 32 + pp * 8]);
    }
#pragma unroll
    for (int m = 0; m < 4; ++m)
#pragma unroll
      for (int n = 0; n < 4; ++n)
        acc[m][n] = __builtin_amdgcn_mfma_f32_16x16x32_bf16(a[m], b[n], acc[m][n], 0, 0, 0);
    __syncthreads();
  }
  // phase 1: d = S - 2*dot + cc ; post wave row-mins; overwrite acc with d
  float ccv[4];
#pragma unroll
  for (int n = 0; n < 4; ++n) ccv[n] = cc[n0 + wc * 64 + n * 16 + rl];
#pragma unroll
  for (int m = 0; m < 4; ++m) {
#pragma unroll
    for (int j = 0; j < 4; ++j) {
      const int gr = m0 + wr * 64 + m * 16 + lh * 4 + j;
      const bool valid = gr < M;
      const float Sv = valid ? S[gr] : 0.f;
      float mn = 3.4e38f;
#pragma unroll
      for (int n = 0; n < 4; ++n) {
        const float d = fmaf(-2.f, acc[m][n][j], Sv) + ccv[n];
        acc[m][n][j] = d;
        mn = fminf(mn, d);
      }
#pragma unroll
      for (int mask = 1; mask < 16; mask <<= 1)
        mn = fminf(mn, __shfl_xor(mn, mask, 64));
      if (valid && rl == 0) atomicMin(&rowmin[gr], ordered_bits(mn));
    }
  }
  // make own atomics visible to own subsequent loads (drain + L1 invalidate)
  __threadfence();
  // phase 2: candidate append vs observed (>= final) row-min -> superset
#pragma unroll
  for (int m = 0; m < 4; ++m) {
#pragma unroll
    for (int j = 0; j < 4; ++j) {
      const int gr = m0 + wr * 64 + m * 16 + lh * 4 + j;
      if (gr >= M) continue;
      const float thr = unordered_bits(rowmin[gr]) + kMargin;
#pragma unroll
      for (int n = 0; n < 4; ++n) {
        if (acc[m][n][j] <= thr) {
          const unsigned gc = (unsigned)(n0 + wc * 64 + n * 16 + rl);
          const unsigned slot = atomicAdd(counter, 1u);
          if (slot < kCap) cands[slot] = (unsigned)gr * 8192u + gc;
        }
      }
    }
  }
}

// ---------------- exact fp32 rescore of candidates ----------------
__global__ __launch_bounds__(256) void rescore(
    const float* __restrict__ X, const float* __restrict__ Cn,
    const float* __restrict__ S, const float* __restrict__ cc,
    const unsigned* __restrict__ cands, const unsigned* __restrict__ counter,
    u64* __restrict__ keys) {
  const unsigned nc = min(*counter, kCap);
  const int l = threadIdx.x & 63;
  const unsigned wglob = (blockIdx.x * 256 + threadIdx.x) >> 6;
  const unsigned nw = (gridDim.x * 256) >> 6;
  for (unsigned i = wglob; i < nc; i += nw) {
    const unsigned pc = cands[i];
    const int r = pc >> 13, c = pc & 8191;
    const float4* xr = reinterpret_cast<const float4*>(X + (size_t)r * kC);
    const float4* cr = reinterpret_cast<const float4*>(Cn + (size_t)c * kC);
    float acc = 0.f;
#pragma unroll
    for (int q = 0; q < 4; ++q) {
      const float4 a = xr[l * 4 + q], b = cr[l * 4 + q];
      acc = fmaf(a.x, b.x, acc); acc = fmaf(a.y, b.y, acc);
      acc = fmaf(a.z, b.z, acc); acc = fmaf(a.w, b.w, acc);
    }
#pragma unroll
    for (int off = 32; off > 0; off >>= 1) acc += __shfl_down(acc, off, 64);
    if (l == 0) {
      const float d = (S[r] - 2.0f * acc) + cc[c];   // exact ref association
      atomicMin(&keys[r], ((u64)ordered_bits(d) << 32) | (unsigned)c);
    }
  }
}

// ---------------- fused distance-GEMM + argmin (exact fp32; RVQ path) ------
__global__ __launch_bounds__(256) void vq_argmin(
    const float* __restrict__ A, const float* __restrict__ table,
    const float* __restrict__ cc, const float* __restrict__ S,
    u64* __restrict__ keys, int M, int Kd) {
  __shared__ float As[16][128];
  __shared__ float Ts[16][128];
  __shared__ u64 red[128][16];
  const int m0 = blockIdx.x * 128, n0 = blockIdx.y * 128;
  const int t = threadIdx.x;
  const int tx = t & 15, ty = t >> 4;
  const int lrow = t >> 1, lk8 = (t & 1) * 8;
  float acc[8][8] = {};
  for (int k0 = 0; k0 < Kd; k0 += 16) {
    const int gm = m0 + lrow;
    float4 a0 = make_float4(0.f, 0.f, 0.f, 0.f), a1 = a0;
    if (gm < M) {
      const float* ap = &A[(size_t)gm * Kd + (k0 + lk8)];
      a0 = *reinterpret_cast<const float4*>(ap);
      a1 = *reinterpret_cast<const float4*>(ap + 4);
    }
    const float* tp = &table[(size_t)(n0 + lrow) * Kd + (k0 + lk8)];
    const float4 b0 = *reinterpret_cast<const float4*>(tp);
    const float4 b1 = *reinterpret_cast<const float4*>(tp + 4);
    As[lk8 + 0][lrow] = a0.x; As[lk8 + 1][lrow] = a0.y;
    As[lk8 + 2][lrow] = a0.z; As[lk8 + 3][lrow] = a0.w;
    As[lk8 + 4][lrow] = a1.x; As[lk8 + 5][lrow] = a1.y;
    As[lk8 + 6][lrow] = a1.z; As[lk8 + 7][lrow] = a1.w;
    Ts[lk8 + 0][lrow] = b0.x; Ts[lk8 + 1][lrow] = b0.y;
    Ts[lk8 + 2][lrow] = b0.z; Ts[lk8 + 3][lrow] = b0.w;
    Ts[lk8 + 4][lrow] = b1.x; Ts[lk8 + 5][lrow] = b1.y;
    Ts[lk8 + 6][lrow] = b1.z; Ts[lk8 + 7][lrow] = b1.w;
    __syncthreads();
#pragma unroll
    for (int kk = 0; kk < 16; ++kk) {
      float ar[8], br[8];
      *reinterpret_cast<float4*>(&ar[0]) = *reinterpret_cast<const float4*>(&As[kk][ty * 8]);
      *reinterpret_cast<float4*>(&ar[4]) = *reinterpret_cast<const float4*>(&As[kk][ty * 8 + 4]);
      *reinterpret_cast<float4*>(&br[0]) = *reinterpret_cast<const float4*>(&Ts[kk][tx * 8]);
      *reinterpret_cast<float4*>(&br[4]) = *reinterpret_cast<const float4*>(&Ts[kk][tx * 8 + 4]);
#pragma unroll
      for (int i = 0; i < 8; ++i)
#pragma unroll
        for (int j = 0; j < 8; ++j) acc[i][j] = fmaf(ar[i], br[j], acc[i][j]);
    }
    __syncthreads();
  }
  float ccv[8];
  *reinterpret_cast<float4*>(&ccv[0]) = *reinterpret_cast<const float4*>(&cc[n0 + tx * 8]);
  *reinterpret_cast<float4*>(&ccv[4]) = *reinterpret_cast<const float4*>(&cc[n0 + tx * 8 + 4]);
#pragma unroll
  for (int i = 0; i < 8; ++i) {
    const int gm = m0 + ty * 8 + i;
    const float Srow = (gm < M) ? S[gm] : 0.f;
    u64 best = ~0ull;
#pragma unroll
    for (int j = 0; j < 8; ++j) {
      const int gn = n0 + tx * 8 + j;
      const float d = (Srow - 2.0f * acc[i][j]) + ccv[j];
      const u64 key = ((u64)ordered_bits(d) << 32) | (unsigned)gn;
      best = (key < best) ? key : best;
    }
    red[ty * 8 + i][tx] = best;
  }
  __syncthreads();
  if (t < 128) {
    u64 b = red[t][0];
#pragma unroll
    for (int j = 1; j < 16; ++j) { const u64 v = red[t][j]; b = (v < b) ? v : b; }
    const int gm = m0 + t;
    if (gm < M) atomicMin(&keys[gm], b);
  }
}

// ---------------- gather centroid + form residual (in-place on X) ----------
__global__ __launch_bounds__(256) void gather_residual(
    const float* __restrict__ centroid, const u64* __restrict__ keys,
    float* __restrict__ X, float* __restrict__ lin_dec) {
  const int i4 = blockIdx.x * 256 + threadIdx.x;
  const int n = i4 >> 8;
  const int c4 = (i4 & 255) << 2;
  const unsigned idx = (unsigned)(keys[n] & 0xffffffffu);
  const float4 cv = *reinterpret_cast<const float4*>(&centroid[(size_t)idx * kC + c4]);
  float4 xv = *reinterpret_cast<const float4*>(&X[(size_t)n * kC + c4]);
  xv.x -= cv.x; xv.y -= cv.y; xv.z -= cv.z; xv.w -= cv.w;
  *reinterpret_cast<float4*>(&lin_dec[(size_t)n * kC + c4]) = cv;
  *reinterpret_cast<float4*>(&X[(size_t)n * kC + c4]) = xv;
}

// ---------------- generic GEMM: out = act(A @ W + bias) ----------------
template <int ACT>   // 0 = none, 1 = leaky relu, 2 = relu
__global__ __launch_bounds__(256) void gemm_bias_act(
    const float* __restrict__ A, const float* __restrict__ W,
    const float* __restrict__ bias, float* __restrict__ out,
    int M, int Nc, int Kd) {
  __shared__ float As[16][64];
  __shared__ float Ws[16][64];
  const int m0 = blockIdx.x * 64, n0 = blockIdx.y * 64;
  const int t = threadIdx.x;
  const int tx = t & 15, ty = t >> 4;
  const int arow = t >> 2, ak4 = (t & 3) << 2;
  const int wk = t >> 4, wn4 = (t & 15) << 2;
  float acc[4][4] = {};
  for (int k0 = 0; k0 < Kd; k0 += 16) {
    float4 av = make_float4(0.f, 0.f, 0.f, 0.f);
    const int gm = m0 + arow;
    if (gm < M) av = *reinterpret_cast<const float4*>(&A[(size_t)gm * Kd + (k0 + ak4)]);
    As[ak4 + 0][arow] = av.x; As[ak4 + 1][arow] = av.y;
    As[ak4 + 2][arow] = av.z; As[ak4 + 3][arow] = av.w;
    *reinterpret_cast<float4*>(&Ws[wk][wn4]) =
        *reinterpret_cast<const float4*>(&W[(size_t)(k0 + wk) * Nc + (n0 + wn4)]);
    __syncthreads();
#pragma unroll
    for (int kk = 0; kk < 16; ++kk) {
      float ar[4], br[4];
      *reinterpret_cast<float4*>(ar) = *reinterpret_cast<const float4*>(&As[kk][ty << 2]);
      *reinterpret_cast<float4*>(br) = *reinterpret_cast<const float4*>(&Ws[kk][tx << 2]);
#pragma unroll
      for (int i = 0; i < 4; ++i)
#pragma unroll
        for (int j = 0; j < 4; ++j) acc[i][j] = fmaf(ar[i], br[j], acc[i][j]);
    }
    __syncthreads();
  }
  float bv[4];
  *reinterpret_cast<float4*>(bv) = *reinterpret_cast<const float4*>(&bias[n0 + (tx << 2)]);
#pragma unroll
  for (int i = 0; i < 4; ++i) {
    const int gm = m0 + (ty << 2) + i;
    if (gm >= M) continue;
    float o[4];
#pragma unroll
    for (int j = 0; j < 4; ++j) {
      float v = acc[i][j] + bv[j];
      if (ACT == 1) v = (v >= 0.f) ? v : kSlope * v;
      if (ACT == 2) v = fmaxf(v, 0.f);
      o[j] = v;
    }
    *reinterpret_cast<float4*>(&out[(size_t)gm * Nc + n0 + (tx << 2)]) =
        *reinterpret_cast<const float4*>(o);
  }
}

// ---------------- resid = enc/(norm+eps); qsum = 0 ----------------
__global__ __launch_bounds__(256) void norm_div_init(
    const float* __restrict__ e, const float* __restrict__ nv,
    float* __restrict__ resid, float* __restrict__ qsum) {
  const int i = blockIdx.x * 256 + threadIdx.x;
  const float4 ev = reinterpret_cast<const float4*>(e)[i];
  const float4 vv = reinterpret_cast<const float4*>(nv)[i];
  float4 r;
  r.x = ev.x / (vv.x + kEps); r.y = ev.y / (vv.y + kEps);
  r.z = ev.z / (vv.z + kEps); r.w = ev.w / (vv.w + kEps);
  reinterpret_cast<float4*>(resid)[i] = r;
  reinterpret_cast<float4*>(qsum)[i] = make_float4(0.f, 0.f, 0.f, 0.f);
}

// ---------------- q = cb[idx]; qsum += q; resid -= q ----------------
__global__ __launch_bounds__(256) void rvq_update(
    const float* __restrict__ cb, const u64* __restrict__ keys,
    float* __restrict__ resid, float* __restrict__ qsum) {
  const int i4 = blockIdx.x * 256 + threadIdx.x;
  const int n = i4 >> 6;
  const int d4 = (i4 & 63) << 2;
  const unsigned idx = (unsigned)(keys[n] & 0xffffffffu);
  const float4 q = *reinterpret_cast<const float4*>(&cb[(size_t)idx * kD + d4]);
  float4 r = reinterpret_cast<float4*>(resid)[i4];
  float4 s = reinterpret_cast<float4*>(qsum)[i4];
  r.x -= q.x; r.y -= q.y; r.z -= q.z; r.w -= q.w;
  s.x += q.x; s.y += q.y; s.z += q.z; s.w += q.w;
  reinterpret_cast<float4*>(resid)[i4] = r;
  reinterpret_cast<float4*>(qsum)[i4] = s;
}

// ---------------- dec_in = qsum * norm_vec ----------------
__global__ __launch_bounds__(256) void denorm(
    const float* __restrict__ qsum, const float* __restrict__ nv,
    float* __restrict__ o) {
  const int i = blockIdx.x * 256 + threadIdx.x;
  const float4 q = reinterpret_cast<const float4*>(qsum)[i];
  const float4 v = reinterpret_cast<const float4*>(nv)[i];
  float4 r;
  r.x = q.x * v.x; r.y = q.y * v.y; r.z = q.z * v.z; r.w = q.w * v.w;
  reinterpret_cast<float4*>(o)[i] = r;
}

// ---------------- out[b,c,t] = lin_dec[n,c] + dec_out[n,c] ----------------
__global__ __launch_bounds__(256) void final_out(const float* __restrict__ lin_dec,
                                                 const float* __restrict__ dec_out,
                                                 float* __restrict__ out) {
  __shared__ float tile[32][33];
  const int t0 = blockIdx.x * 32, c0 = blockIdx.y * 32, b = blockIdx.z;
  const int tx = threadIdx.x, ty = threadIdx.y;
#pragma unroll
  for (int i = 0; i < 4; ++i) {
    const int tl = ty + i * 8;
    if (t0 + tl < kT) {
      const size_t idx = (size_t)(b * kT + t0 + tl) * kC + (c0 + tx);
      tile[tl][tx] = lin_dec[idx] + dec_out[idx];
    }
  }
  __syncthreads();
#pragma unroll
  for (int i = 0; i < 4; ++i) {
    const int cl = ty + i * 8;
    if (t0 + tx < kT)
      out[(size_t)b * kC * kT + (size_t)(c0 + cl) * kT + (t0 + tx)] = tile[tx][cl];
  }
}

}  // namespace

extern "C" void kernel_launch(void* const* d_in, const int* in_sizes, int n_in,
                              void* d_out, int out_size, void* d_ws, size_t ws_size,
                              hipStream_t stream) {
  (void)in_sizes; (void)n_in; (void)out_size; (void)ws_size;
  const float* feature  = (const float*)d_in[0];
  const float* centroid = (const float*)d_in[1];
  const float* enc_w0 = (const float*)d_in[2];  const float* enc_b0 = (const float*)d_in[3];
  const float* enc_w1 = (const float*)d_in[4];  const float* enc_b1 = (const float*)d_in[5];
  const float* enc_w2 = (const float*)d_in[6];  const float* enc_b2 = (const float*)d_in[7];
  const float* dec_w0 = (const float*)d_in[8];  const float* dec_b0 = (const float*)d_in[9];
  const float* dec_w1 = (const float*)d_in[10]; const float* dec_b1 = (const float*)d_in[11];
  const float* dec_w2 = (const float*)d_in[12]; const float* dec_b2 = (const float*)d_in[13];
  const float* nrm_w0 = (const float*)d_in[14]; const float* nrm_b0 = (const float*)d_in[15];
  const float* nrm_w1 = (const float*)d_in[16]; const float* nrm_b1 = (const float*)d_in[17];
  const float* nrm_w2 = (const float*)d_in[18]; const float* nrm_b2 = (const float*)d_in[19];
  const float* codebooks = (const float*)d_in[20];
  float* out = (float*)d_out;

  // workspace layout (~197 MB footprint)
  float* X       = (float*)d_ws;                 // N*C : x_flat -> spk_raw -> dec_out
  float* lin_dec = X       + (size_t)kN * kC;    // N*C   (aliased: cands during lin VQ)
  float* h0      = lin_dec + (size_t)kN * kC;    // N*H   (aliased: xh bf16 during lin VQ)
  float* h1      = h0      + (size_t)kN * kH;    // N*H   (aliased: ch bf16 + rowmin/ctr)
  float* e_out   = h1      + (size_t)kN * kH;    // N*D
  float* nvec    = e_out   + (size_t)kN * kD;    // N*D
  float* resid   = nvec    + (size_t)kN * kD;    // N*D
  float* qsum    = resid   + (size_t)kN * kD;    // N*D
  float* Srow    = qsum    + (size_t)kN * kD;    // N
  float* ccbuf   = Srow    + kN;                 // max(K, BINS)
  u64*   keys    = (u64*)(ccbuf + kK);           // N packed (dist,idx)

  // aliases, dead until later stages:
  unsigned short* xh = (unsigned short*)h0;       // N*C bf16 (fills h0 exactly)
  unsigned short* ch = (unsigned short*)h1;       // K*C bf16 (4.19M floats of h1)
  unsigned* cands    = (unsigned*)lin_dec;        // kCap u32 = 4M floats < 6.14M  OK
  unsigned* rowmin   = (unsigned*)(h1 + 4500000); // N u32
  unsigned* counter  = rowmin + kN;               // 1 u32   (4.5M+12K+1 < 6.14M  OK)

  const dim3 tb32(32, 8);
  const dim3 tgT((kT + 31) / 32, kC / 32, kB);

  transpose_in<<<tgT, tb32, 0, stream>>>(feature, X);

  // ---- linguistic VQ: bf16-MFMA candidate pass + exact fp32 rescore ----
  row_sqsum<<<kN, 256, 0, stream>>>(X, Srow, kC);
  row_sqsum<<<kK, 256, 0, stream>>>(centroid, ccbuf, kC);
  to_bf16<<<(kN * kC / 4 + 255) / 256, 256, 0, stream>>>(X, xh, kN * kC / 4);
  to_bf16<<<(kK * kC / 4 + 255) / 256, 256, 0, stream>>>(centroid, ch, kK * kC / 4);
  hipMemsetAsync(rowmin, 0xFF, (size_t)kN * sizeof(unsigned), stream);
  hipMemsetAsync(counter, 0x00, sizeof(unsigned), stream);
  hipMemsetAsync(keys, 0xFF, (size_t)kN * sizeof(u64), stream);
  lin_vq_mfma<<<dim3((kN + 127) / 128, kK / 128), 256, 0, stream>>>(
      xh, ch, Srow, ccbuf, rowmin, cands, counter, kN);
  rescore<<<512, 256, 0, stream>>>(X, centroid, Srow, ccbuf, cands, counter, keys);
  gather_residual<<<kN * kC / 4 / 256, 256, 0, stream>>>(centroid, keys, X, lin_dec);

  const dim3 gH((kN + 63) / 64, kH / 64);
  const dim3 gD((kN + 63) / 64, kD / 64);
  const dim3 gC((kN + 63) / 64, kC / 64);

  // ---- encoder (leaky, leaky, none) on spk_raw (X) ----
  gemm_bias_act<1><<<gH, 256, 0, stream>>>(X,  enc_w0, enc_b0, h0,    kN, kH, kC);
  gemm_bias_act<1><<<gH, 256, 0, stream>>>(h0, enc_w1, enc_b1, h1,    kN, kH, kH);
  gemm_bias_act<0><<<gD, 256, 0, stream>>>(h1, enc_w2, enc_b2, e_out, kN, kD, kH);

  // ---- normalizer (relu x3) on lin_dec ----
  gemm_bias_act<2><<<gH, 256, 0, stream>>>(lin_dec, nrm_w0, nrm_b0, h0,   kN, kH, kC);
  gemm_bias_act<2><<<gH, 256, 0, stream>>>(h0,      nrm_w1, nrm_b1, h1,   kN, kH, kH);
  gemm_bias_act<2><<<gD, 256, 0, stream>>>(h1,      nrm_w2, nrm_b2, nvec, kN, kD, kH);

  norm_div_init<<<kN * kD / 4 / 256, 256, 0, stream>>>(e_out, nvec, resid, qsum);

  // ---- RVQ: 4 stages (exact fp32 path — absorption ties require it) ----
  for (int q = 0; q < kNQ; ++q) {
    const float* cb = codebooks + (size_t)q * kBins * kD;
    row_sqsum<<<kN, 256, 0, stream>>>(resid, Srow, kD);
    row_sqsum<<<kBins, 256, 0, stream>>>(cb, ccbuf, kD);
    hipMemsetAsync(keys, 0xFF, (size_t)kN * sizeof(u64), stream);
    vq_argmin<<<dim3((kN + 127) / 128, kBins / 128), 256, 0, stream>>>(
        resid, cb, ccbuf, Srow, keys, kN, kD);
    rvq_update<<<kN * kD / 4 / 256, 256, 0, stream>>>(cb, keys, resid, qsum);
  }

  denorm<<<kN * kD / 4 / 256, 256, 0, stream>>>(qsum, nvec, e_out);

  // ---- decoder (leaky, leaky, none) ----
  gemm_bias_act<1><<<gH, 256, 0, stream>>>(e_out, dec_w0, dec_b0, h0, kN, kH, kD);
  gemm_bias_act<1><<<gH, 256, 0, stream>>>(h0,    dec_w1, dec_b1, h1, kN, kH, kH);
  gemm_bias_act<0><<<gC, 256, 0, stream>>>(h1,    dec_w2, dec_b2, X,  kN, kC, kH);

  final_out<<<tgT, tb32, 0, stream>>>(lin_dec, X, out);
}

// Round 5
// 2469.326 us; speedup vs baseline: 1.6149x; 1.1315x over previous
//
#include <hip/hip_runtime.h>

namespace {

constexpr int kB = 8;
constexpr int kC = 1024;
constexpr int kT = 1500;
constexpr int kK = 8192;
constexpr int kD = 256;
constexpr int kH = 512;
constexpr int kNQ = 4;
constexpr int kBins = 1024;
constexpr int kN = kB * kT;       // 12000 frames
constexpr float kEps = 1e-8f;
constexpr float kSlope = 0.01f;
constexpr float kMargin = 8.0f;    // ~28-57 sigma of bf16-hh distance error
constexpr unsigned kCap = 4194304; // candidate capacity (16 MB, in lin_dec region)

using u64 = unsigned long long;
typedef __attribute__((ext_vector_type(8))) short bf16x8;
typedef __attribute__((ext_vector_type(4))) float f32x4;

__device__ __forceinline__ unsigned ordered_bits(float f) {
  unsigned b = __float_as_uint(f);
  return (b & 0x80000000u) ? ~b : (b | 0x80000000u);
}
__device__ __forceinline__ float unordered_bits(unsigned b) {
  return __uint_as_float((b & 0x80000000u) ? (b ^ 0x80000000u) : ~b);
}
__device__ __forceinline__ unsigned short f2bf(float f) {  // RNE
  unsigned u = __float_as_uint(f);
  return (unsigned short)((u + 0x7fffu + ((u >> 16) & 1u)) >> 16);
}
__device__ __forceinline__ void gl_lds16(const void* g, void* l) {
  __builtin_amdgcn_global_load_lds(
      (const __attribute__((address_space(1))) void*)g,
      (__attribute__((address_space(3))) void*)l, 16, 0, 0);
}

// stage one 128x32 bf16 tile (rows r0..r0+127, k-cols k0..k0+31) into LDS via
// global_load_lds(16B), inverse-swizzled global source so swizzled ds_read
// lands conflict-light. Per wave: 2 issues x 16 rows. (validated in round 4)
__device__ __forceinline__ void stage_tile(const unsigned short* __restrict__ g,
                                           int rowlen, int r0, int k0,
                                           unsigned short* lds,
                                           int w, int srow, int sp) {
#pragma unroll
  for (int i = 0; i < 2; ++i) {
    const int rb = (w * 2 + i) * 16;
    const int r = rb + srow;
    const int s = (sp - ((r >> 1) & 3)) & 3;   // logical slot for phys sp
    gl_lds16(g + ((size_t)(r0 + r) * rowlen + k0 + s * 8), lds + rb * 32);
  }
}

// ---------------- (B,C,T) -> row-major (B*T, C) ----------------
__global__ __launch_bounds__(256) void transpose_in(const float* __restrict__ f,
                                                    float* __restrict__ X) {
  __shared__ float tile[32][33];
  const int t0 = blockIdx.x * 32, c0 = blockIdx.y * 32, b = blockIdx.z;
  const int tx = threadIdx.x, ty = threadIdx.y;
#pragma unroll
  for (int i = 0; i < 4; ++i) {
    const int cl = ty + i * 8;
    if (t0 + tx < kT)
      tile[cl][tx] = f[(size_t)b * kC * kT + (size_t)(c0 + cl) * kT + (t0 + tx)];
  }
  __syncthreads();
#pragma unroll
  for (int i = 0; i < 4; ++i) {
    const int tl = ty + i * 8;
    if (t0 + tl < kT)
      X[(size_t)(b * kT + t0 + tl) * kC + (c0 + tx)] = tile[tx][tl];
  }
}

// ---------------- fp32 -> bf16 convert ----------------
__global__ __launch_bounds__(256) void to_bf16(const float* __restrict__ in,
                                               unsigned short* __restrict__ out,
                                               int n4) {
  const int i = blockIdx.x * 256 + threadIdx.x;
  if (i >= n4) return;
  const float4 v = reinterpret_cast<const float4*>(in)[i];
  ushort4 o;
  o.x = f2bf(v.x); o.y = f2bf(v.y); o.z = f2bf(v.z); o.w = f2bf(v.w);
  reinterpret_cast<ushort4*>(out)[i] = o;
}

// ---------------- fp32 W[K][N] -> bf16 WT[N][K] ----------------
__global__ __launch_bounds__(256) void transpose_w_bf16(
    const float* __restrict__ W, unsigned short* __restrict__ WT, int K, int N) {
  __shared__ float tile[32][33];
  const int k0 = blockIdx.x * 32, n0 = blockIdx.y * 32;
  const int tx = threadIdx.x, ty = threadIdx.y;
#pragma unroll
  for (int i = 0; i < 4; ++i)
    tile[ty + i * 8][tx] = W[(size_t)(k0 + ty + i * 8) * N + (n0 + tx)];
  __syncthreads();
#pragma unroll
  for (int i = 0; i < 4; ++i)
    WT[(size_t)(n0 + ty + i * 8) * K + (k0 + tx)] = f2bf(tile[tx][ty + i * 8]);
}

// ---------------- per-row squared norms ----------------
__global__ __launch_bounds__(256) void row_sqsum(const float* __restrict__ A,
                                                 float* __restrict__ S, int Kd) {
  const int r = blockIdx.x;
  const float4* a4 = reinterpret_cast<const float4*>(A + (size_t)r * Kd);
  float s = 0.f;
  for (int i = threadIdx.x; i < (Kd >> 2); i += 256) {
    const float4 v = a4[i];
    s = fmaf(v.x, v.x, s); s = fmaf(v.y, v.y, s);
    s = fmaf(v.z, v.z, s); s = fmaf(v.w, v.w, s);
  }
#pragma unroll
  for (int off = 32; off > 0; off >>= 1) s += __shfl_down(s, off, 64);
  __shared__ float ws[4];
  const int lane = threadIdx.x & 63, w = threadIdx.x >> 6;
  if (lane == 0) ws[w] = s;
  __syncthreads();
  if (threadIdx.x == 0) S[r] = (ws[0] + ws[1]) + (ws[2] + ws[3]);
}

// ---------------- linguistic VQ: bf16 MFMA approx pass (v2) ----------------
// 128x128 tile, 2-phase prefetch: issue global_load_lds for K-step t+1 into
// the other LDS buffer BEFORE computing step t; the single __syncthreads per
// step (vmcnt(0)+lgkmcnt(0) drain + barrier) then lands AFTER the compute
// phase, so HBM/L3 latency overlaps MFMA. Bijective XCD swizzle gives each
// XCD 8 contiguous column panels (B panel set 2MB -> L2-hot).
__global__ __launch_bounds__(256) void lin_vq_mfma(
    const unsigned short* __restrict__ Ah, const unsigned short* __restrict__ Bh,
    const float* __restrict__ S, const float* __restrict__ cc,
    unsigned* __restrict__ rowmin, unsigned* __restrict__ cands,
    unsigned* __restrict__ counter, int M) {
  __shared__ __attribute__((aligned(16))) unsigned short lsa[2][128 * 32];
  __shared__ __attribute__((aligned(16))) unsigned short lsb[2][128 * 32];
  const int t = threadIdx.x;
  const int l = t & 63, w = t >> 6;
  const int wr = w >> 1, wc = w & 1;
  const int rl = l & 15, lh = l >> 4;
  const int srow = l >> 2, sp = l & 3;
  // bijective XCD swizzle (nwg = 94*64 = 6016, divisible by 8)
  const unsigned nbx = gridDim.x;
  const unsigned flat = blockIdx.y * nbx + blockIdx.x;
  const unsigned q8 = (nbx * gridDim.y) >> 3;
  const unsigned swz = (flat & 7u) * q8 + (flat >> 3);
  const int m0 = (int)(swz % nbx) * 128, n0 = (int)(swz / nbx) * 128;

  f32x4 acc[4][4] = {};
  stage_tile(Ah, kC, m0, 0, lsa[0], w, srow, sp);
  stage_tile(Bh, kC, n0, 0, lsb[0], w, srow, sp);
  __syncthreads();
  for (int kt = 0; kt < kC / 32; ++kt) {
    const int p = kt & 1;
    if (kt + 1 < kC / 32) {   // prefetch next K-step into other buffer
      stage_tile(Ah, kC, m0, (kt + 1) * 32, lsa[p ^ 1], w, srow, sp);
      stage_tile(Bh, kC, n0, (kt + 1) * 32, lsb[p ^ 1], w, srow, sp);
    }
    bf16x8 a[4], b[4];
#pragma unroll
    for (int m = 0; m < 4; ++m) {
      const int r = wr * 64 + m * 16 + rl;
      const int pp = (lh + ((r >> 1) & 3)) & 3;
      a[m] = *reinterpret_cast<const bf16x8*>(&lsa[p][r * 32 + pp * 8]);
    }
#pragma unroll
    for (int n = 0; n < 4; ++n) {
      const int r = wc * 64 + n * 16 + rl;
      const int pp = (lh + ((r >> 1) & 3)) & 3;
      b[n] = *reinterpret_cast<const bf16x8*>(&lsb[p][r * 32 + pp * 8]);
    }
#pragma unroll
    for (int m = 0; m < 4; ++m)
#pragma unroll
      for (int n = 0; n < 4; ++n)
        acc[m][n] = __builtin_amdgcn_mfma_f32_16x16x32_bf16(a[m], b[n], acc[m][n], 0, 0, 0);
    __syncthreads();   // drains prefetch (vmcnt0) + all ds_reads, then barrier
  }
  // phase 1: d = S - 2*dot + cc ; post wave row-mins; overwrite acc with d
  float ccv[4];
#pragma unroll
  for (int n = 0; n < 4; ++n) ccv[n] = cc[n0 + wc * 64 + n * 16 + rl];
#pragma unroll
  for (int m = 0; m < 4; ++m) {
#pragma unroll
    for (int j = 0; j < 4; ++j) {
      const int gr = m0 + wr * 64 + m * 16 + lh * 4 + j;
      const bool valid = gr < M;
      const float Sv = valid ? S[gr] : 0.f;
      float mn = 3.4e38f;
#pragma unroll
      for (int n = 0; n < 4; ++n) {
        const float d = fmaf(-2.f, acc[m][n][j], Sv) + ccv[n];
        acc[m][n][j] = d;
        mn = fminf(mn, d);
      }
#pragma unroll
      for (int mask = 1; mask < 16; mask <<= 1)
        mn = fminf(mn, __shfl_xor(mn, mask, 64));
      if (valid && rl == 0) atomicMin(&rowmin[gr], ordered_bits(mn));
    }
  }
  // make own atomics visible to own subsequent loads (drain + L1 invalidate)
  __threadfence();
  // phase 2: candidate append vs observed (>= final) row-min -> superset
#pragma unroll
  for (int m = 0; m < 4; ++m) {
#pragma unroll
    for (int j = 0; j < 4; ++j) {
      const int gr = m0 + wr * 64 + m * 16 + lh * 4 + j;
      if (gr >= M) continue;
      const float thr = unordered_bits(rowmin[gr]) + kMargin;
#pragma unroll
      for (int n = 0; n < 4; ++n) {
        if (acc[m][n][j] <= thr) {
          const unsigned gc = (unsigned)(n0 + wc * 64 + n * 16 + rl);
          const unsigned slot = atomicAdd(counter, 1u);
          if (slot < kCap) cands[slot] = (unsigned)gr * 8192u + gc;
        }
      }
    }
  }
}

// ---------------- decoder GEMM: bf16 MFMA, out = act(A @ W + b) ----------
// A: M x K bf16 row-major; WT: N x K bf16 (transposed weights). Same staging
// skeleton + 2-phase prefetch as lin_vq_mfma. OUTBF: write bf16 (chained
// layer) or fp32 (final layer).
template <int ACT, int OUTBF>
__global__ __launch_bounds__(256) void gemm_bf16(
    const unsigned short* __restrict__ A, const unsigned short* __restrict__ WT,
    const float* __restrict__ bias, void* __restrict__ outp,
    int M, int N, int K) {
  __shared__ __attribute__((aligned(16))) unsigned short lsa[2][128 * 32];
  __shared__ __attribute__((aligned(16))) unsigned short lsb[2][128 * 32];
  const int t = threadIdx.x;
  const int l = t & 63, w = t >> 6;
  const int wr = w >> 1, wc = w & 1;
  const int rl = l & 15, lh = l >> 4;
  const int srow = l >> 2, sp = l & 3;
  const unsigned nbx = gridDim.x;
  const unsigned nwg = nbx * gridDim.y;
  const unsigned flat = blockIdx.y * nbx + blockIdx.x;
  unsigned swz = flat;
  if ((nwg & 7u) == 0) swz = (flat & 7u) * (nwg >> 3) + (flat >> 3);
  const int m0 = (int)(swz % nbx) * 128, n0 = (int)(swz / nbx) * 128;

  f32x4 acc[4][4] = {};
  stage_tile(A, K, m0, 0, lsa[0], w, srow, sp);
  stage_tile(WT, K, n0, 0, lsb[0], w, srow, sp);
  __syncthreads();
  const int NT = K >> 5;
  for (int kt = 0; kt < NT; ++kt) {
    const int p = kt & 1;
    if (kt + 1 < NT) {
      stage_tile(A, K, m0, (kt + 1) * 32, lsa[p ^ 1], w, srow, sp);
      stage_tile(WT, K, n0, (kt + 1) * 32, lsb[p ^ 1], w, srow, sp);
    }
    bf16x8 a[4], b[4];
#pragma unroll
    for (int m = 0; m < 4; ++m) {
      const int r = wr * 64 + m * 16 + rl;
      const int pp = (lh + ((r >> 1) & 3)) & 3;
      a[m] = *reinterpret_cast<const bf16x8*>(&lsa[p][r * 32 + pp * 8]);
    }
#pragma unroll
    for (int n = 0; n < 4; ++n) {
      const int r = wc * 64 + n * 16 + rl;
      const int pp = (lh + ((r >> 1) & 3)) & 3;
      b[n] = *reinterpret_cast<const bf16x8*>(&lsb[p][r * 32 + pp * 8]);
    }
#pragma unroll
    for (int m = 0; m < 4; ++m)
#pragma unroll
      for (int n = 0; n < 4; ++n)
        acc[m][n] = __builtin_amdgcn_mfma_f32_16x16x32_bf16(a[m], b[n], acc[m][n], 0, 0, 0);
    __syncthreads();
  }
  float bv[4];
#pragma unroll
  for (int n = 0; n < 4; ++n) bv[n] = bias[n0 + wc * 64 + n * 16 + rl];
#pragma unroll
  for (int m = 0; m < 4; ++m) {
#pragma unroll
    for (int j = 0; j < 4; ++j) {
      const int gr = m0 + wr * 64 + m * 16 + lh * 4 + j;
      if (gr >= M) continue;
#pragma unroll
      for (int n = 0; n < 4; ++n) {
        float v = acc[m][n][j] + bv[n];
        if (ACT == 1) v = (v >= 0.f) ? v : kSlope * v;
        const int gc = n0 + wc * 64 + n * 16 + rl;
        if (OUTBF) ((unsigned short*)outp)[(size_t)gr * N + gc] = f2bf(v);
        else       ((float*)outp)[(size_t)gr * N + gc] = v;
      }
    }
  }
}

// ---------------- exact fp32 rescore of candidates ----------------
__global__ __launch_bounds__(256) void rescore(
    const float* __restrict__ X, const float* __restrict__ Cn,
    const float* __restrict__ S, const float* __restrict__ cc,
    const unsigned* __restrict__ cands, const unsigned* __restrict__ counter,
    u64* __restrict__ keys) {
  const unsigned nc = min(*counter, kCap);
  const int l = threadIdx.x & 63;
  const unsigned wglob = (blockIdx.x * 256 + threadIdx.x) >> 6;
  const unsigned nw = (gridDim.x * 256) >> 6;
  for (unsigned i = wglob; i < nc; i += nw) {
    const unsigned pc = cands[i];
    const int r = pc >> 13, c = pc & 8191;
    const float4* xr = reinterpret_cast<const float4*>(X + (size_t)r * kC);
    const float4* cr = reinterpret_cast<const float4*>(Cn + (size_t)c * kC);
    float acc = 0.f;
#pragma unroll
    for (int q = 0; q < 4; ++q) {
      const float4 a = xr[l * 4 + q], b = cr[l * 4 + q];
      acc = fmaf(a.x, b.x, acc); acc = fmaf(a.y, b.y, acc);
      acc = fmaf(a.z, b.z, acc); acc = fmaf(a.w, b.w, acc);
    }
#pragma unroll
    for (int off = 32; off > 0; off >>= 1) acc += __shfl_down(acc, off, 64);
    if (l == 0) {
      const float d = (S[r] - 2.0f * acc) + cc[c];   // exact ref association
      atomicMin(&keys[r], ((u64)ordered_bits(d) << 32) | (unsigned)c);
    }
  }
}

// ---------------- fused distance-GEMM + argmin (exact fp32; RVQ path) ------
__global__ __launch_bounds__(256) void vq_argmin(
    const float* __restrict__ A, const float* __restrict__ table,
    const float* __restrict__ cc, const float* __restrict__ S,
    u64* __restrict__ keys, int M, int Kd) {
  __shared__ float As[16][128];
  __shared__ float Ts[16][128];
  __shared__ u64 red[128][16];
  const int m0 = blockIdx.x * 128, n0 = blockIdx.y * 128;
  const int t = threadIdx.x;
  const int tx = t & 15, ty = t >> 4;
  const int lrow = t >> 1, lk8 = (t & 1) * 8;
  float acc[8][8] = {};
  for (int k0 = 0; k0 < Kd; k0 += 16) {
    const int gm = m0 + lrow;
    float4 a0 = make_float4(0.f, 0.f, 0.f, 0.f), a1 = a0;
    if (gm < M) {
      const float* ap = &A[(size_t)gm * Kd + (k0 + lk8)];
      a0 = *reinterpret_cast<const float4*>(ap);
      a1 = *reinterpret_cast<const float4*>(ap + 4);
    }
    const float* tp = &table[(size_t)(n0 + lrow) * Kd + (k0 + lk8)];
    const float4 b0 = *reinterpret_cast<const float4*>(tp);
    const float4 b1 = *reinterpret_cast<const float4*>(tp + 4);
    As[lk8 + 0][lrow] = a0.x; As[lk8 + 1][lrow] = a0.y;
    As[lk8 + 2][lrow] = a0.z; As[lk8 + 3][lrow] = a0.w;
    As[lk8 + 4][lrow] = a1.x; As[lk8 + 5][lrow] = a1.y;
    As[lk8 + 6][lrow] = a1.z; As[lk8 + 7][lrow] = a1.w;
    Ts[lk8 + 0][lrow] = b0.x; Ts[lk8 + 1][lrow] = b0.y;
    Ts[lk8 + 2][lrow] = b0.z; Ts[lk8 + 3][lrow] = b0.w;
    Ts[lk8 + 4][lrow] = b1.x; Ts[lk8 + 5][lrow] = b1.y;
    Ts[lk8 + 6][lrow] = b1.z; Ts[lk8 + 7][lrow] = b1.w;
    __syncthreads();
#pragma unroll
    for (int kk = 0; kk < 16; ++kk) {
      float ar[8], br[8];
      *reinterpret_cast<float4*>(&ar[0]) = *reinterpret_cast<const float4*>(&As[kk][ty * 8]);
      *reinterpret_cast<float4*>(&ar[4]) = *reinterpret_cast<const float4*>(&As[kk][ty * 8 + 4]);
      *reinterpret_cast<float4*>(&br[0]) = *reinterpret_cast<const float4*>(&Ts[kk][tx * 8]);
      *reinterpret_cast<float4*>(&br[4]) = *reinterpret_cast<const float4*>(&Ts[kk][tx * 8 + 4]);
#pragma unroll
      for (int i = 0; i < 8; ++i)
#pragma unroll
        for (int j = 0; j < 8; ++j) acc[i][j] = fmaf(ar[i], br[j], acc[i][j]);
    }
    __syncthreads();
  }
  float ccv[8];
  *reinterpret_cast<float4*>(&ccv[0]) = *reinterpret_cast<const float4*>(&cc[n0 + tx * 8]);
  *reinterpret_cast<float4*>(&ccv[4]) = *reinterpret_cast<const float4*>(&cc[n0 + tx * 8 + 4]);
#pragma unroll
  for (int i = 0; i < 8; ++i) {
    const int gm = m0 + ty * 8 + i;
    const float Srow = (gm < M) ? S[gm] : 0.f;
    u64 best = ~0ull;
#pragma unroll
    for (int j = 0; j < 8; ++j) {
      const int gn = n0 + tx * 8 + j;
      const float d = (Srow - 2.0f * acc[i][j]) + ccv[j];
      const u64 key = ((u64)ordered_bits(d) << 32) | (unsigned)gn;
      best = (key < best) ? key : best;
    }
    red[ty * 8 + i][tx] = best;
  }
  __syncthreads();
  if (t < 128) {
    u64 b = red[t][0];
#pragma unroll
    for (int j = 1; j < 16; ++j) { const u64 v = red[t][j]; b = (v < b) ? v : b; }
    const int gm = m0 + t;
    if (gm < M) atomicMin(&keys[gm], b);
  }
}

// ---------------- gather centroid + form residual (in-place on X) ----------
__global__ __launch_bounds__(256) void gather_residual(
    const float* __restrict__ centroid, const u64* __restrict__ keys,
    float* __restrict__ X, float* __restrict__ lin_dec) {
  const int i4 = blockIdx.x * 256 + threadIdx.x;
  const int n = i4 >> 8;
  const int c4 = (i4 & 255) << 2;
  const unsigned idx = (unsigned)(keys[n] & 0xffffffffu);
  const float4 cv = *reinterpret_cast<const float4*>(&centroid[(size_t)idx * kC + c4]);
  float4 xv = *reinterpret_cast<const float4*>(&X[(size_t)n * kC + c4]);
  xv.x -= cv.x; xv.y -= cv.y; xv.z -= cv.z; xv.w -= cv.w;
  *reinterpret_cast<float4*>(&lin_dec[(size_t)n * kC + c4]) = cv;
  *reinterpret_cast<float4*>(&X[(size_t)n * kC + c4]) = xv;
}

// ---------------- generic fp32 GEMM (enc/nrm — numerics frozen) ----------
template <int ACT>   // 0 = none, 1 = leaky relu, 2 = relu
__global__ __launch_bounds__(256) void gemm_bias_act(
    const float* __restrict__ A, const float* __restrict__ W,
    const float* __restrict__ bias, float* __restrict__ out,
    int M, int Nc, int Kd) {
  __shared__ float As[16][64];
  __shared__ float Ws[16][64];
  const int m0 = blockIdx.x * 64, n0 = blockIdx.y * 64;
  const int t = threadIdx.x;
  const int tx = t & 15, ty = t >> 4;
  const int arow = t >> 2, ak4 = (t & 3) << 2;
  const int wk = t >> 4, wn4 = (t & 15) << 2;
  float acc[4][4] = {};
  for (int k0 = 0; k0 < Kd; k0 += 16) {
    float4 av = make_float4(0.f, 0.f, 0.f, 0.f);
    const int gm = m0 + arow;
    if (gm < M) av = *reinterpret_cast<const float4*>(&A[(size_t)gm * Kd + (k0 + ak4)]);
    As[ak4 + 0][arow] = av.x; As[ak4 + 1][arow] = av.y;
    As[ak4 + 2][arow] = av.z; As[ak4 + 3][arow] = av.w;
    *reinterpret_cast<float4*>(&Ws[wk][wn4]) =
        *reinterpret_cast<const float4*>(&W[(size_t)(k0 + wk) * Nc + (n0 + wn4)]);
    __syncthreads();
#pragma unroll
    for (int kk = 0; kk < 16; ++kk) {
      float ar[4], br[4];
      *reinterpret_cast<float4*>(ar) = *reinterpret_cast<const float4*>(&As[kk][ty << 2]);
      *reinterpret_cast<float4*>(br) = *reinterpret_cast<const float4*>(&Ws[kk][tx << 2]);
#pragma unroll
      for (int i = 0; i < 4; ++i)
#pragma unroll
        for (int j = 0; j < 4; ++j) acc[i][j] = fmaf(ar[i], br[j], acc[i][j]);
    }
    __syncthreads();
  }
  float bv[4];
  *reinterpret_cast<float4*>(bv) = *reinterpret_cast<const float4*>(&bias[n0 + (tx << 2)]);
#pragma unroll
  for (int i = 0; i < 4; ++i) {
    const int gm = m0 + (ty << 2) + i;
    if (gm >= M) continue;
    float o[4];
#pragma unroll
    for (int j = 0; j < 4; ++j) {
      float v = acc[i][j] + bv[j];
      if (ACT == 1) v = (v >= 0.f) ? v : kSlope * v;
      if (ACT == 2) v = fmaxf(v, 0.f);
      o[j] = v;
    }
    *reinterpret_cast<float4*>(&out[(size_t)gm * Nc + n0 + (tx << 2)]) =
        *reinterpret_cast<const float4*>(o);
  }
}

// ---------------- resid = enc/(norm+eps); qsum = 0 ----------------
__global__ __launch_bounds__(256) void norm_div_init(
    const float* __restrict__ e, const float* __restrict__ nv,
    float* __restrict__ resid, float* __restrict__ qsum) {
  const int i = blockIdx.x * 256 + threadIdx.x;
  const float4 ev = reinterpret_cast<const float4*>(e)[i];
  const float4 vv = reinterpret_cast<const float4*>(nv)[i];
  float4 r;
  r.x = ev.x / (vv.x + kEps); r.y = ev.y / (vv.y + kEps);
  r.z = ev.z / (vv.z + kEps); r.w = ev.w / (vv.w + kEps);
  reinterpret_cast<float4*>(resid)[i] = r;
  reinterpret_cast<float4*>(qsum)[i] = make_float4(0.f, 0.f, 0.f, 0.f);
}

// ---------------- q = cb[idx]; qsum += q; resid -= q ----------------
__global__ __launch_bounds__(256) void rvq_update(
    const float* __restrict__ cb, const u64* __restrict__ keys,
    float* __restrict__ resid, float* __restrict__ qsum) {
  const int i4 = blockIdx.x * 256 + threadIdx.x;
  const int n = i4 >> 6;
  const int d4 = (i4 & 63) << 2;
  const unsigned idx = (unsigned)(keys[n] & 0xffffffffu);
  const float4 q = *reinterpret_cast<const float4*>(&cb[(size_t)idx * kD + d4]);
  float4 r = reinterpret_cast<float4*>(resid)[i4];
  float4 s = reinterpret_cast<float4*>(qsum)[i4];
  r.x -= q.x; r.y -= q.y; r.z -= q.z; r.w -= q.w;
  s.x += q.x; s.y += q.y; s.z += q.z; s.w += q.w;
  reinterpret_cast<float4*>(resid)[i4] = r;
  reinterpret_cast<float4*>(qsum)[i4] = s;
}

// ---------------- dec_in(bf16) = qsum * norm_vec ----------------
__global__ __launch_bounds__(256) void denorm_bf16(
    const float* __restrict__ qsum, const float* __restrict__ nv,
    unsigned short* __restrict__ o) {
  const int i = blockIdx.x * 256 + threadIdx.x;
  const float4 q = reinterpret_cast<const float4*>(qsum)[i];
  const float4 v = reinterpret_cast<const float4*>(nv)[i];
  ushort4 r;
  r.x = f2bf(q.x * v.x); r.y = f2bf(q.y * v.y);
  r.z = f2bf(q.z * v.z); r.w = f2bf(q.w * v.w);
  reinterpret_cast<ushort4*>(o)[i] = r;
}

// ---------------- out[b,c,t] = lin_dec[n,c] + dec_out[n,c] ----------------
__global__ __launch_bounds__(256) void final_out(const float* __restrict__ lin_dec,
                                                 const float* __restrict__ dec_out,
                                                 float* __restrict__ out) {
  __shared__ float tile[32][33];
  const int t0 = blockIdx.x * 32, c0 = blockIdx.y * 32, b = blockIdx.z;
  const int tx = threadIdx.x, ty = threadIdx.y;
#pragma unroll
  for (int i = 0; i < 4; ++i) {
    const int tl = ty + i * 8;
    if (t0 + tl < kT) {
      const size_t idx = (size_t)(b * kT + t0 + tl) * kC + (c0 + tx);
      tile[tl][tx] = lin_dec[idx] + dec_out[idx];
    }
  }
  __syncthreads();
#pragma unroll
  for (int i = 0; i < 4; ++i) {
    const int cl = ty + i * 8;
    if (t0 + tx < kT)
      out[(size_t)b * kC * kT + (size_t)(c0 + cl) * kT + (t0 + tx)] = tile[tx][cl];
  }
}

}  // namespace

extern "C" void kernel_launch(void* const* d_in, const int* in_sizes, int n_in,
                              void* d_out, int out_size, void* d_ws, size_t ws_size,
                              hipStream_t stream) {
  (void)in_sizes; (void)n_in; (void)out_size; (void)ws_size;
  const float* feature  = (const float*)d_in[0];
  const float* centroid = (const float*)d_in[1];
  const float* enc_w0 = (const float*)d_in[2];  const float* enc_b0 = (const float*)d_in[3];
  const float* enc_w1 = (const float*)d_in[4];  const float* enc_b1 = (const float*)d_in[5];
  const float* enc_w2 = (const float*)d_in[6];  const float* enc_b2 = (const float*)d_in[7];
  const float* dec_w0 = (const float*)d_in[8];  const float* dec_b0 = (const float*)d_in[9];
  const float* dec_w1 = (const float*)d_in[10]; const float* dec_b1 = (const float*)d_in[11];
  const float* dec_w2 = (const float*)d_in[12]; const float* dec_b2 = (const float*)d_in[13];
  const float* nrm_w0 = (const float*)d_in[14]; const float* nrm_b0 = (const float*)d_in[15];
  const float* nrm_w1 = (const float*)d_in[16]; const float* nrm_b1 = (const float*)d_in[17];
  const float* nrm_w2 = (const float*)d_in[18]; const float* nrm_b2 = (const float*)d_in[19];
  const float* codebooks = (const float*)d_in[20];
  float* out = (float*)d_out;

  // workspace layout (~197 MB footprint, unchanged)
  float* X       = (float*)d_ws;                 // N*C
  float* lin_dec = X       + (size_t)kN * kC;    // N*C (alias: cands during lin VQ)
  float* h0      = lin_dec + (size_t)kN * kC;    // N*H (alias: xh; later h0b + wT)
  float* h1      = h0      + (size_t)kN * kH;    // N*H (alias: ch + rowmin/ctr; h1b)
  float* e_out   = h1      + (size_t)kN * kH;    // N*D (alias: dec_in_bf)
  float* nvec    = e_out   + (size_t)kN * kD;    // N*D
  float* resid   = nvec    + (size_t)kN * kD;    // N*D
  float* qsum    = resid   + (size_t)kN * kD;    // N*D
  float* Srow    = qsum    + (size_t)kN * kD;    // N
  float* ccbuf   = Srow    + kN;                 // max(K, BINS)
  u64*   keys    = (u64*)(ccbuf + kK);           // N packed (dist,idx)

  // aliases, dead until their stage:
  unsigned short* xh = (unsigned short*)h0;       // N*C bf16 (fills h0 exactly)
  unsigned short* ch = (unsigned short*)h1;       // K*C bf16 (4.19M floats of h1)
  unsigned* cands    = (unsigned*)lin_dec;        // kCap u32 = 4M floats < 12.29M
  unsigned* rowmin   = (unsigned*)(h1 + 4500000); // N u32
  unsigned* counter  = rowmin + kN;               // 1 u32
  // decoder-stage aliases:
  unsigned short* dec_in_bf = (unsigned short*)e_out;        // N*D bf16
  unsigned short* h0b = (unsigned short*)h0;                 // N*H bf16 (3.07M fl)
  unsigned short* h1b = (unsigned short*)h1;                 // N*H bf16
  unsigned short* wT0 = (unsigned short*)(h0 + 3200000);     // 512x256 bf16
  unsigned short* wT1 = wT0 + (size_t)kH * kD;               // 512x512 bf16
  unsigned short* wT2 = wT1 + (size_t)kH * kH;               // 1024x512 bf16

  const dim3 tb32(32, 8);
  const dim3 tgT((kT + 31) / 32, kC / 32, kB);

  transpose_in<<<tgT, tb32, 0, stream>>>(feature, X);

  // ---- linguistic VQ: bf16-MFMA candidate pass + exact fp32 rescore ----
  row_sqsum<<<kN, 256, 0, stream>>>(X, Srow, kC);
  row_sqsum<<<kK, 256, 0, stream>>>(centroid, ccbuf, kC);
  to_bf16<<<(kN * kC / 4 + 255) / 256, 256, 0, stream>>>(X, xh, kN * kC / 4);
  to_bf16<<<(kK * kC / 4 + 255) / 256, 256, 0, stream>>>(centroid, ch, kK * kC / 4);
  hipMemsetAsync(rowmin, 0xFF, (size_t)kN * sizeof(unsigned), stream);
  hipMemsetAsync(counter, 0x00, sizeof(unsigned), stream);
  hipMemsetAsync(keys, 0xFF, (size_t)kN * sizeof(u64), stream);
  lin_vq_mfma<<<dim3((kN + 127) / 128, kK / 128), 256, 0, stream>>>(
      xh, ch, Srow, ccbuf, rowmin, cands, counter, kN);
  rescore<<<512, 256, 0, stream>>>(X, centroid, Srow, ccbuf, cands, counter, keys);
  gather_residual<<<kN * kC / 4 / 256, 256, 0, stream>>>(centroid, keys, X, lin_dec);

  const dim3 gH((kN + 63) / 64, kH / 64);
  const dim3 gD((kN + 63) / 64, kD / 64);

  // ---- encoder (fp32, numerics frozen) on spk_raw (X) ----
  gemm_bias_act<1><<<gH, 256, 0, stream>>>(X,  enc_w0, enc_b0, h0,    kN, kH, kC);
  gemm_bias_act<1><<<gH, 256, 0, stream>>>(h0, enc_w1, enc_b1, h1,    kN, kH, kH);
  gemm_bias_act<0><<<gD, 256, 0, stream>>>(h1, enc_w2, enc_b2, e_out, kN, kD, kH);

  // ---- normalizer (fp32, numerics frozen) on lin_dec ----
  gemm_bias_act<2><<<gH, 256, 0, stream>>>(lin_dec, nrm_w0, nrm_b0, h0,   kN, kH, kC);
  gemm_bias_act<2><<<gH, 256, 0, stream>>>(h0,      nrm_w1, nrm_b1, h1,   kN, kH, kH);
  gemm_bias_act<2><<<gD, 256, 0, stream>>>(h1,      nrm_w2, nrm_b2, nvec, kN, kD, kH);

  norm_div_init<<<kN * kD / 4 / 256, 256, 0, stream>>>(e_out, nvec, resid, qsum);

  // ---- RVQ: 4 stages (exact fp32 path — absorption ties require it) ----
  for (int q = 0; q < kNQ; ++q) {
    const float* cb = codebooks + (size_t)q * kBins * kD;
    row_sqsum<<<kN, 256, 0, stream>>>(resid, Srow, kD);
    row_sqsum<<<kBins, 256, 0, stream>>>(cb, ccbuf, kD);
    hipMemsetAsync(keys, 0xFF, (size_t)kN * sizeof(u64), stream);
    vq_argmin<<<dim3((kN + 127) / 128, kBins / 128), 256, 0, stream>>>(
        resid, cb, ccbuf, Srow, keys, kN, kD);
    rvq_update<<<kN * kD / 4 / 256, 256, 0, stream>>>(cb, keys, resid, qsum);
  }

  // ---- decoder: bf16 MFMA (safe: q_sum path exact; only spk_dec ~0.4% rel) --
  transpose_w_bf16<<<dim3(kD / 32, kH / 32), tb32, 0, stream>>>(dec_w0, wT0, kD, kH);
  transpose_w_bf16<<<dim3(kH / 32, kH / 32), tb32, 0, stream>>>(dec_w1, wT1, kH, kH);
  transpose_w_bf16<<<dim3(kH / 32, kC / 32), tb32, 0, stream>>>(dec_w2, wT2, kH, kC);
  denorm_bf16<<<kN * kD / 4 / 256, 256, 0, stream>>>(qsum, nvec, dec_in_bf);
  gemm_bf16<1, 1><<<dim3((kN + 127) / 128, kH / 128), 256, 0, stream>>>(
      dec_in_bf, wT0, dec_b0, h0b, kN, kH, kD);
  gemm_bf16<1, 1><<<dim3((kN + 127) / 128, kH / 128), 256, 0, stream>>>(
      h0b, wT1, dec_b1, h1b, kN, kH, kH);
  gemm_bf16<0, 0><<<dim3((kN + 127) / 128, kC / 128), 256, 0, stream>>>(
      h1b, wT2, dec_b2, X, kN, kC, kH);

  final_out<<<tgT, tb32, 0, stream>>>(lin_dec, X, out);
}